// Round 4
// baseline (168.968 us; speedup 1.0000x reference)
//
#include <hip/hip_runtime.h>
#include <math.h>

#define D_MODEL 1024
#define N_RES   2048
#define BATCH   32
constexpr float INV_2PI = 0.15915494309189535f;

// ws layout (floats):
#define WS_XC 0
#define WS_CS (32 * 1024)
#define WS_SS (WS_CS + 32 * 2048)
#define WS_PA (WS_SS + 32 * 2048)
#define WS_PR (WS_PA + 2 * 32 * 1024)
#define WS_PI (WS_PR + 4 * 32 * 1024)

// ---------------------------------------------------------------------------
// kA_partial: split-K half of x_collapsed. blockIdx = dtile(256) + 256*kc(2).
// (unchanged from R3 — this round's delta is attributable to kB only)
// ---------------------------------------------------------------------------
__global__ __launch_bounds__(256) void kA_partial(const float* __restrict__ xr,
                                                  const float* __restrict__ xi,
                                                  const float* __restrict__ ipw,
                                                  float* __restrict__ pa) {
  const int tid  = threadIdx.x;
  const int lane = tid & 63;
  const int wave = tid >> 6;
  const int d0 = (blockIdx.x & 255) * 4;
  const int kc = blockIdx.x >> 8;
  const int b0 = wave * 8;

  const float4* x4p  = (const float4*)(kc ? xi : xr);  // 256 f4 per row
  const float4* ipw4 = (const float4*)ipw;             // 512 f4 per row
  const int woff = kc * 256;

  float acc[8][4];
#pragma unroll
  for (int b = 0; b < 8; ++b)
#pragma unroll
    for (int d = 0; d < 4; ++d) acc[b][d] = 0.f;

#pragma unroll 1
  for (int i = 0; i < 4; ++i) {
    const int j = lane + 64 * i;   // f4 idx in [0,256)
    float4 w4[4];
#pragma unroll
    for (int d = 0; d < 4; ++d) w4[d] = ipw4[(d0 + d) * 512 + woff + j];
#pragma unroll
    for (int b = 0; b < 8; ++b) {
      float4 x4 = x4p[(b0 + b) * 256 + j];
#pragma unroll
      for (int d = 0; d < 4; ++d) {
        acc[b][d] += x4.x * w4[d].x + x4.y * w4[d].y + x4.z * w4[d].z + x4.w * w4[d].w;
      }
    }
  }

#pragma unroll
  for (int b = 0; b < 8; ++b) {
#pragma unroll
    for (int d = 0; d < 4; ++d) {
      float v = acc[b][d];
#pragma unroll
      for (int m = 32; m >= 1; m >>= 1) v += __shfl_xor(v, m, 64);
      if (lane == 0) pa[(size_t)(kc * BATCH + b0 + b) * D_MODEL + d0 + d] = v;
    }
  }
}

// kA2: xc = pa[0] + pa[1] + bias. 8192 float4 -> 32 blocks.
__global__ __launch_bounds__(256) void kA2(const float* __restrict__ pa,
                                           const float* __restrict__ bias,
                                           float* __restrict__ xc) {
  const int idx = blockIdx.x * 256 + threadIdx.x;
  const float4* pa4 = (const float4*)pa;
  const float4* b4p = (const float4*)bias;
  float4 a = pa4[idx];
  float4 b = pa4[8192 + idx];
  float4 c = b4p[idx & 255];
  float4 r;
  r.x = a.x + b.x + c.x;
  r.y = a.y + b.y + c.y;
  r.z = a.z + b.z + c.z;
  r.w = a.w + b.w + c.w;
  ((float4*)xc)[idx] = r;
}

// ---------------------------------------------------------------------------
// kB v2: block-per-n (2048 blocks, 4 waves). Changes vs v1:
//  - coefficients a=INV_2PI/(1+|W|), c=B*INV_2PI computed per-WAVE directly
//    from global into REGISTERS (av/cv, 8 f4) — v1 re-read the same 8 LDS
//    b128 values 8x per wave (64 ds_reads); also removes LDS + barrier.
//  - v_fract_f32 via builtin instead of floorf+sub (2 ops -> 1).
//  - 4 split accumulators (break the serial add chain feeding the trans pipe)
//  - next batch's xc row prefetched into regs while current computes
//    (decouple ~200-300cyc L2 latency from the trans pipe).
// Issue model/wave: 8bb x [32 trans x 8cyc + ~64 VALU x 2cyc] ~= 3.4k cyc
// -> ~14us at 5 waves/SIMD.
// ---------------------------------------------------------------------------
__global__ __launch_bounds__(256) void kB(const float* __restrict__ xc,
                                          const float* __restrict__ W,
                                          const float* __restrict__ Bm,
                                          const float* __restrict__ t,
                                          float* __restrict__ cos_sum,
                                          float* __restrict__ sin_sum) {
  const int n    = blockIdx.x;
  const int tid  = threadIdx.x;
  const int lane = tid & 63;
  const int wave = tid >> 6;
  const int b0   = wave * 8;

  // Per-wave register-resident coefficients for all 1024 d's (f4 stride 64).
  const float4* W4 = (const float4*)(W + (size_t)n * D_MODEL);
  const float4* B4 = (const float4*)(Bm + (size_t)n * D_MODEL);
  float4 av[4], cv[4];
#pragma unroll
  for (int i = 0; i < 4; ++i) {
    float4 w4 = W4[lane + 64 * i];
    float4 b4 = B4[lane + 64 * i];
    av[i].x = INV_2PI / (1.f + fabsf(w4.x));
    av[i].y = INV_2PI / (1.f + fabsf(w4.y));
    av[i].z = INV_2PI / (1.f + fabsf(w4.z));
    av[i].w = INV_2PI / (1.f + fabsf(w4.w));
    cv[i].x = b4.x * INV_2PI;
    cv[i].y = b4.y * INV_2PI;
    cv[i].z = b4.z * INV_2PI;
    cv[i].w = b4.w * INV_2PI;
  }

  float t2v[8];
#pragma unroll
  for (int bb = 0; bb < 8; ++bb) t2v[bb] = t[b0 + bb] * INV_2PI;

  // prefetch batch b0's xc row
  float4 xcur[4], xnxt[4];
  {
    const float4* x0 = (const float4*)(xc + (size_t)b0 * D_MODEL);
#pragma unroll
    for (int i = 0; i < 4; ++i) xcur[i] = x0[lane + 64 * i];
  }

#pragma unroll 1
  for (int bb = 0; bb < 8; ++bb) {
    if (bb < 7) {
      const float4* xn = (const float4*)(xc + (size_t)(b0 + bb + 1) * D_MODEL);
#pragma unroll
      for (int i = 0; i < 4; ++i) xnxt[i] = xn[lane + 64 * i];
    }
    const float t2 = t2v[bb];
    float ss0 = 0.f, ss1 = 0.f, cc0 = 0.f, cc1 = 0.f;
#pragma unroll
    for (int i = 0; i < 4; ++i) {
      float4 x4 = xcur[i];
      float4 a4 = av[i];
      float4 c4 = cv[i];
      {
        float r = __builtin_amdgcn_fractf(x4.x * a4.x + c4.x + t2);
        ss0 += __builtin_amdgcn_sinf(r);
        cc0 += __builtin_amdgcn_cosf(r);
      }
      {
        float r = __builtin_amdgcn_fractf(x4.y * a4.y + c4.y + t2);
        ss1 += __builtin_amdgcn_sinf(r);
        cc1 += __builtin_amdgcn_cosf(r);
      }
      {
        float r = __builtin_amdgcn_fractf(x4.z * a4.z + c4.z + t2);
        ss0 += __builtin_amdgcn_sinf(r);
        cc0 += __builtin_amdgcn_cosf(r);
      }
      {
        float r = __builtin_amdgcn_fractf(x4.w * a4.w + c4.w + t2);
        ss1 += __builtin_amdgcn_sinf(r);
        cc1 += __builtin_amdgcn_cosf(r);
      }
    }
    float ss = ss0 + ss1;
    float cc = cc0 + cc1;
#pragma unroll
    for (int m = 32; m >= 1; m >>= 1) {
      ss += __shfl_xor(ss, m, 64);
      cc += __shfl_xor(cc, m, 64);
    }
    if (lane == 0) {
      const int b = b0 + bb;
      cos_sum[(size_t)b * N_RES + n] = cc;
      sin_sum[(size_t)b * N_RES + n] = ss;
    }
#pragma unroll
    for (int i = 0; i < 4; ++i) xcur[i] = xnxt[i];
  }
}

// ---------------------------------------------------------------------------
// kC_partial: split-K output GEMM (unchanged from R3).
// ---------------------------------------------------------------------------
__global__ __launch_bounds__(256) void kC_partial(const float* __restrict__ cos_sum,
                                                  const float* __restrict__ sin_sum,
                                                  const float* __restrict__ orw,
                                                  const float* __restrict__ oiw,
                                                  float* __restrict__ pr,
                                                  float* __restrict__ pi) {
  const int tid  = threadIdx.x;
  const int lane = tid & 63;
  const int wave = tid >> 6;
  const int d0 = (blockIdx.x & 255) * 4;
  const int kc = blockIdx.x >> 8;
  const int b0 = wave * 8;
  const int jbase = kc * 128;

  float ar[8][4], ai[8][4];
#pragma unroll
  for (int b = 0; b < 8; ++b)
#pragma unroll
    for (int d = 0; d < 4; ++d) { ar[b][d] = 0.f; ai[b][d] = 0.f; }

#pragma unroll 1
  for (int i = 0; i < 2; ++i) {
    const int j = jbase + lane + 64 * i;
    float4 wr[4], wi[4];
#pragma unroll
    for (int d = 0; d < 4; ++d) {
      wr[d] = ((const float4*)(orw + (size_t)(d0 + d) * N_RES))[j];
      wi[d] = ((const float4*)(oiw + (size_t)(d0 + d) * N_RES))[j];
    }
#pragma unroll
    for (int b = 0; b < 8; ++b) {
      float4 cs = ((const float4*)(cos_sum + (size_t)(b0 + b) * N_RES))[j];
      float4 sn = ((const float4*)(sin_sum + (size_t)(b0 + b) * N_RES))[j];
#pragma unroll
      for (int d = 0; d < 4; ++d) {
        ar[b][d] += cs.x * wr[d].x + cs.y * wr[d].y + cs.z * wr[d].z + cs.w * wr[d].w;
        ai[b][d] += sn.x * wi[d].x + sn.y * wi[d].y + sn.z * wi[d].z + sn.w * wi[d].w;
      }
    }
  }

#pragma unroll
  for (int b = 0; b < 8; ++b) {
#pragma unroll
    for (int d = 0; d < 4; ++d) {
      float vr = ar[b][d];
      float vi = ai[b][d];
#pragma unroll
      for (int m = 32; m >= 1; m >>= 1) {
        vr += __shfl_xor(vr, m, 64);
        vi += __shfl_xor(vi, m, 64);
      }
      if (lane == 0) {
        const size_t o = (size_t)(kc * BATCH + b0 + b) * D_MODEL + d0 + d;
        pr[o] = vr;
        pi[o] = vi;
      }
    }
  }
}

__device__ __forceinline__ float silu(float v) { return v / (1.f + __expf(-v)); }

__global__ __launch_bounds__(256) void kC2(const float* __restrict__ pr,
                                           const float* __restrict__ pi,
                                           float* __restrict__ out) {
  const int idx = blockIdx.x * 256 + threadIdx.x;
  const float4* pr4 = (const float4*)pr;
  const float4* pi4 = (const float4*)pi;
  float4 vr = pr4[idx];
  float4 vi = pi4[idx];
#pragma unroll
  for (int kc = 1; kc < 4; ++kc) {
    float4 a = pr4[kc * 8192 + idx];
    float4 b = pi4[kc * 8192 + idx];
    vr.x += a.x; vr.y += a.y; vr.z += a.z; vr.w += a.w;
    vi.x += b.x; vi.y += b.y; vi.z += b.z; vi.w += b.w;
  }
  float4 orr, oii;
  orr.x = silu(vr.x); orr.y = silu(vr.y); orr.z = silu(vr.z); orr.w = silu(vr.w);
  oii.x = silu(vi.x); oii.y = silu(vi.y); oii.z = silu(vi.z); oii.w = silu(vi.w);
  ((float4*)out)[idx] = orr;
  ((float4*)out)[8192 + idx] = oii;
}

extern "C" void kernel_launch(void* const* d_in, const int* in_sizes, int n_in,
                              void* d_out, int out_size, void* d_ws, size_t ws_size,
                              hipStream_t stream) {
  const float* xr   = (const float*)d_in[0];
  const float* xi   = (const float*)d_in[1];
  const float* t    = (const float*)d_in[2];
  const float* ipw  = (const float*)d_in[3];
  const float* bias = (const float*)d_in[4];
  const float* W    = (const float*)d_in[5];
  const float* Bm   = (const float*)d_in[6];
  const float* orw  = (const float*)d_in[7];
  const float* oiw  = (const float*)d_in[8];
  float* out = (float*)d_out;

  float* ws      = (float*)d_ws;
  float* xc      = ws + WS_XC;
  float* cos_sum = ws + WS_CS;
  float* sin_sum = ws + WS_SS;
  float* pa      = ws + WS_PA;
  float* pr      = ws + WS_PR;
  float* pi      = ws + WS_PI;

  kA_partial<<<512, 256, 0, stream>>>(xr, xi, ipw, pa);
  kA2<<<32, 256, 0, stream>>>(pa, bias, xc);
  kB<<<N_RES, 256, 0, stream>>>(xc, W, Bm, t, cos_sum, sin_sum);
  kC_partial<<<1024, 256, 0, stream>>>(cos_sum, sin_sum, orw, oiw, pr, pi);
  kC2<<<32, 256, 0, stream>>>(pr, pi, out);
}